// Round 4
// baseline (145.511 us; speedup 1.0000x reference)
//
#include <hip/hip_runtime.h>
#include <math.h>

// StreamingTransformer: B=8, S=1000, C=512, H=8, D=64, L=6.
// Facts exploited:
//  (1) x is loop-invariant in the reference -> only layer 5 matters.
//  (2) scores = qk*0.125 + (i-j); keys j >= 128 contribute < e^-120 -> truncate
//      attention (and K/V projection) to 128 keys.
//  (3) softmax shift-invariance with analytic shift (i+2) -> no max-reduction.
// Round 8 = Round 7 resubmit (container infra failure, no kernel signal).
// Launch-count experiment (H1: ~29us/launch overhead dominates; R1 fit 266-237=29,
// R0/R2 both ~140 with 4 launches regardless of work moved).
// 4 -> 3 launches: kv-projection blocks are SELF-SUFFICIENT (own in-register
// 2-pass LN of the 128 rows/batch they need + own fp32->bf16 W staging) and run
// inside the prep launch. Chain: prep+kv -> attn(Q fused) -> outproj.

typedef __bf16 bf16x8 __attribute__((ext_vector_type(8)));
typedef __bf16 bf16x4 __attribute__((ext_vector_type(4)));
typedef float f32x4 __attribute__((ext_vector_type(4)));

__device__ __forceinline__ void async16(const __bf16* g, __bf16* l) {
  __builtin_amdgcn_global_load_lds((const __attribute__((address_space(1))) void*)g,
                                   (__attribute__((address_space(3))) void*)l, 16, 0, 0);
}

__device__ __forceinline__ bf16x8 norm8(float4 a, float4 c, float4 ga, float4 gc,
                                        float4 ba, float4 bc, float m, float r) {
  bf16x8 o;
  o[0] = (__bf16)((a.x - m) * r * ga.x + ba.x);
  o[1] = (__bf16)((a.y - m) * r * ga.y + ba.y);
  o[2] = (__bf16)((a.z - m) * r * ga.z + ba.z);
  o[3] = (__bf16)((a.w - m) * r * ga.w + ba.w);
  o[4] = (__bf16)((c.x - m) * r * gc.x + bc.x);
  o[5] = (__bf16)((c.y - m) * r * gc.y + bc.y);
  o[6] = (__bf16)((c.z - m) * r * gc.z + bc.z);
  o[7] = (__bf16)((c.w - m) * r * gc.w + bc.w);
  return o;
}

// ---- launch A: blocks 0..127 self-sufficient KV projection;
//      128..639 weight convert (Wq, Wo); 640..2639 LN (4 rows/block) -----------
__global__ __launch_bounds__(256) void prep_kv_k(
    const float* __restrict__ x, const float* __restrict__ lg,
    const float* __restrict__ lb,
    const float* __restrict__ Wq, const float* __restrict__ Wo,
    const float* __restrict__ Wk, const float* __restrict__ Wv,
    const float* __restrict__ bk, const float* __restrict__ bv,
    __bf16* __restrict__ wqb, __bf16* __restrict__ wob,
    __bf16* __restrict__ xn, __bf16* __restrict__ Ykv) {
  __shared__ __align__(16) __bf16 Ws[64 * 512];  // 64 KB (kv blocks only)
  const int t = threadIdx.x;
  const int id = blockIdx.x;

  if (id >= 128) {  // ---- prep paths (no LDS, block-uniform branch)
    int u = id - 128;
    if (u < 512) {  // weight fp32 -> bf16 (Wq: u<256, Wo: u>=256)
      const float* src = (u < 256) ? Wq : Wo;
      __bf16* dst = (u < 256) ? wqb : wob;
      int idx = ((u & 255) * 256 + t) * 4;
      float4 v = *(const float4*)(src + idx);
      bf16x4 o = {(__bf16)v.x, (__bf16)v.y, (__bf16)v.z, (__bf16)v.w};
      *(bf16x4*)(dst + idx) = o;
      return;
    }
    // LN: 4 rows/block
    const int row = (u - 512) * 4 + (t >> 6);
    const int l = t & 63;
    const float* xr = x + (size_t)row * 512 + l * 8;
    float4 a = *(const float4*)xr, c = *(const float4*)(xr + 4);
    float s = a.x + a.y + a.z + a.w + c.x + c.y + c.z + c.w;
#pragma unroll
    for (int m = 1; m < 64; m <<= 1) s += __shfl_xor(s, m, 64);
    float mean = s * (1.0f / 512.0f);
    float d[8] = {a.x - mean, a.y - mean, a.z - mean, a.w - mean,
                  c.x - mean, c.y - mean, c.z - mean, c.w - mean};
    float qq = 0.f;
#pragma unroll
    for (int e = 0; e < 8; ++e) qq += d[e] * d[e];
#pragma unroll
    for (int m = 1; m < 64; m <<= 1) qq += __shfl_xor(qq, m, 64);
    float rstd = rsqrtf(qq * (1.0f / 512.0f) + 1e-5f);
    float4 g0 = *(const float4*)(lg + l * 8), g1 = *(const float4*)(lg + l * 8 + 4);
    float4 b0 = *(const float4*)(lb + l * 8), b1 = *(const float4*)(lb + l * 8 + 4);
    float gg[8] = {g0.x, g0.y, g0.z, g0.w, g1.x, g1.y, g1.z, g1.w};
    float bb[8] = {b0.x, b0.y, b0.z, b0.w, b1.x, b1.y, b1.z, b1.w};
    bf16x8 o;
#pragma unroll
    for (int e = 0; e < 8; ++e) o[e] = (__bf16)(d[e] * rstd * gg[e] + bb[e]);
    *(bf16x8*)(xn + (size_t)row * 512 + l * 8) = o;
    return;
  }

  // ---- KV projection, self-sufficient (reads only raw inputs) ---------------
  const int w = t >> 6, l = t & 63, g = l >> 4, l15 = l & 15;
  const int b = id & 7, n = id >> 3;  // co-XCD per batch (id%8 = b)
  const float* Wsrc = (n < 8) ? (Wk + (size_t)n * 64 * 512)
                              : (Wv + (size_t)(n - 8) * 64 * 512);
  const float* bp = (n < 8) ? (bk + n * 64) : (bv + (n - 8) * 64);

  // stage W slice: fp32 -> bf16 -> LDS, same swizzle as the bf16 async16 path
#pragma unroll
  for (int i = 0; i < 16; ++i) {
    int s = i * 256 + t;
    int row = s >> 6, u = s & 63;
    const float* gp = Wsrc + (size_t)row * 512 + ((u ^ (row & 7)) << 3);
    float4 f0 = *(const float4*)gp, f1 = *(const float4*)(gp + 4);
    bf16x8 o = {(__bf16)f0.x, (__bf16)f0.y, (__bf16)f0.z, (__bf16)f0.w,
                (__bf16)f1.x, (__bf16)f1.y, (__bf16)f1.z, (__bf16)f1.w};
    *(bf16x8*)&Ws[s * 8] = o;
  }

  // in-register LN stats for this lane's two rows; lanes {l15+16g} share a row
  const int r0 = w * 32 + l15, r1 = r0 + 16;  // < 128 always
  const float* x0 = x + (size_t)(b * 1000 + r0) * 512;
  const float* x1 = x + (size_t)(b * 1000 + r1) * 512;
  float s0 = 0.f, q0 = 0.f, s1 = 0.f, q1 = 0.f;
#pragma unroll
  for (int ks = 0; ks < 16; ++ks) {
    int off = ks * 32 + g * 8;
    float4 a = *(const float4*)(x0 + off), c = *(const float4*)(x0 + off + 4);
    float4 d = *(const float4*)(x1 + off), e = *(const float4*)(x1 + off + 4);
    s0 += a.x + a.y + a.z + a.w + c.x + c.y + c.z + c.w;
    q0 += a.x * a.x + a.y * a.y + a.z * a.z + a.w * a.w +
          c.x * c.x + c.y * c.y + c.z * c.z + c.w * c.w;
    s1 += d.x + d.y + d.z + d.w + e.x + e.y + e.z + e.w;
    q1 += d.x * d.x + d.y * d.y + d.z * d.z + d.w * d.w +
          e.x * e.x + e.y * e.y + e.z * e.z + e.w * e.w;
  }
  s0 += __shfl_xor(s0, 16, 64); q0 += __shfl_xor(q0, 16, 64);
  s1 += __shfl_xor(s1, 16, 64); q1 += __shfl_xor(q1, 16, 64);
  s0 += __shfl_xor(s0, 32, 64); q0 += __shfl_xor(q0, 32, 64);
  s1 += __shfl_xor(s1, 32, 64); q1 += __shfl_xor(q1, 32, 64);
  const float m0 = s0 * (1.f / 512.f), m1 = s1 * (1.f / 512.f);
  const float rst0 = rsqrtf(fmaxf(q0 * (1.f / 512.f) - m0 * m0, 0.f) + 1e-5f);
  const float rst1 = rsqrtf(fmaxf(q1 * (1.f / 512.f) - m1 * m1, 0.f) + 1e-5f);

  float bias_j[4];
#pragma unroll
  for (int j = 0; j < 4; ++j) bias_j[j] = bp[j * 16 + l15];

  __syncthreads();  // W resident

  f32x4 acc[2][4] = {};
#pragma unroll 2
  for (int ks = 0; ks < 16; ++ks) {
    int off = ks * 32 + g * 8;
    float4 ga = *(const float4*)(lg + off), gc = *(const float4*)(lg + off + 4);
    float4 ba = *(const float4*)(lb + off), bc = *(const float4*)(lb + off + 4);
    float4 a = *(const float4*)(x0 + off), c = *(const float4*)(x0 + off + 4);
    float4 d = *(const float4*)(x1 + off), e = *(const float4*)(x1 + off + 4);
    bf16x8 ca0 = norm8(a, c, ga, gc, ba, bc, m0, rst0);
    bf16x8 ca1 = norm8(d, e, ga, gc, ba, bc, m1, rst1);
    bf16x8 bfr[4];
#pragma unroll
    for (int j = 0; j < 4; ++j) {
      int rb = j * 16 + l15;
      int u = ks * 4 + g;
      bfr[j] = *(const bf16x8*)&Ws[rb * 512 + ((u ^ (rb & 7)) << 3)];
    }
#pragma unroll
    for (int j = 0; j < 4; ++j) {
      acc[0][j] = __builtin_amdgcn_mfma_f32_16x16x32_bf16(ca0, bfr[j], acc[0][j], 0, 0, 0);
      acc[1][j] = __builtin_amdgcn_mfma_f32_16x16x32_bf16(ca1, bfr[j], acc[1][j], 0, 0, 0);
    }
  }

  __bf16* Yp = Ykv + (size_t)b * 128 * 1024 + n * 64;
#pragma unroll
  for (int strip = 0; strip < 2; ++strip)
#pragma unroll
    for (int r = 0; r < 4; ++r) {
      int lrow = w * 32 + strip * 16 + g * 4 + r;  // < 128 always
#pragma unroll
      for (int j = 0; j < 4; ++j)
        Yp[(size_t)lrow * 1024 + j * 16 + l15] = (__bf16)(acc[strip][j][r] + bias_j[j]);
    }
}

// ---- fused Q-projection + attention (keys 0..127): block = (b,h) x 64 q-rows --
__global__ __launch_bounds__(256) void attn_k(const __bf16* __restrict__ xn,
                                              const __bf16* __restrict__ wq,
                                              const float* __restrict__ bq,
                                              const __bf16* __restrict__ kv,
                                              __bf16* __restrict__ ctx) {
  __shared__ __align__(16) __bf16 arena[32768];  // 64 KB
  __bf16* Ks = arena;            // 128*64  = 8192
  __bf16* Vt = arena + 8192;     // 64*128  = 8192
  __bf16* Qs = arena + 16384;    // 64*64   = 4096
  __bf16* Ps = arena + 20480;    // 4*16*136= 8704
  const int t = threadIdx.x, w = t >> 6, l = t & 63, g = l >> 4, l15 = l & 15;
  const int id = blockIdx.x;
  const int h = id >> 7, b = (id >> 4) & 7, q0 = (id & 15) * 64;

  // stage Wq head-slice (64 x 512) into the full arena
  const __bf16* Wt = wq + (size_t)h * 64 * 512;
#pragma unroll
  for (int i = 0; i < 16; ++i) {
    int s = i * 256 + t;
    int row = s >> 6, u = s & 63;
    async16(Wt + (size_t)row * 512 + ((u ^ (row & 7)) << 3), &arena[s * 8]);
  }
  int qr = q0 + w * 16 + l15;
  int cqr = (qr > 999) ? 999 : qr;
  const __bf16* a0p = xn + ((size_t)(b * 1000 + cqr)) * 512 + g * 8;
  bf16x8 a0 = *(const bf16x8*)a0p;  // k-step 0 prefetch
  float bias_j[4];
#pragma unroll
  for (int j = 0; j < 4; ++j) bias_j[j] = bq[h * 64 + j * 16 + l15];
  __syncthreads();  // Wq slice resident

  // q-GEMM: (64 x 512) @ slice^T -> 64 x 64
  f32x4 acc[4] = {};
#pragma unroll
  for (int ks = 0; ks < 16; ++ks) {
    bf16x8 ca = a0;
    if (ks < 15) a0 = *(const bf16x8*)(a0p + (ks + 1) * 32);
    bf16x8 bfr[4];
#pragma unroll
    for (int j = 0; j < 4; ++j) {
      int rb = j * 16 + l15;
      int u = ks * 4 + g;
      bfr[j] = *(const bf16x8*)&arena[rb * 512 + ((u ^ (rb & 7)) << 3)];
    }
#pragma unroll
    for (int j = 0; j < 4; ++j)
      acc[j] = __builtin_amdgcn_mfma_f32_16x16x32_bf16(ca, bfr[j], acc[j], 0, 0, 0);
  }
  __syncthreads();  // all waves done with Wq slice; arena reusable

  // stage K (async16) + V (transpose scatter) + q-tile
#pragma unroll
  for (int i = 0; i < 4; ++i) {
    int s = i * 256 + t;
    int row = s >> 3, u = s & 7;
    async16(kv + (size_t)(b * 128 + row) * 1024 + h * 64 + ((u ^ (row & 7)) << 3), &Ks[s * 8]);
  }
  {  // V transpose scatter
    int vrow = t & 127, dbase = (t >> 7) * 32;
    const __bf16* vp = kv + (size_t)(b * 128 + vrow) * 1024 + 512 + h * 64 + dbase;
#pragma unroll
    for (int c = 0; c < 4; ++c) {
      bf16x8 vv = *(const bf16x8*)(vp + c * 8);
#pragma unroll
      for (int e = 0; e < 8; ++e) {
        int d = dbase + c * 8 + e;
        Vt[d * 128 + (((vrow >> 3) ^ (d & 7)) << 3) + (vrow & 7)] = vv[e];
      }
    }
  }
  // q-tile -> Qs (swizzled [64][64]); read back own A-frags (same wave, no barrier)
#pragma unroll
  for (int j = 0; j < 4; ++j)
#pragma unroll
    for (int r = 0; r < 4; ++r) {
      int row = w * 16 + g * 4 + r, col = j * 16 + l15;
      Qs[row * 64 + ((((col >> 3) ^ (row & 7))) << 3) + (col & 7)] =
          (__bf16)(acc[j][r] + bias_j[j]);
    }
  bf16x8 aq[2];
  {
    int row = w * 16 + l15;
    aq[0] = *(const bf16x8*)&Qs[row * 64 + ((g ^ (row & 7)) << 3)];
    aq[1] = *(const bf16x8*)&Qs[row * 64 + (((4 + g) ^ (row & 7)) << 3)];
  }
  __syncthreads();  // Ks/Vt resident

  f32x4 ct[8] = {};
#pragma unroll
  for (int c = 0; c < 2; ++c)
#pragma unroll
    for (int nt = 0; nt < 8; ++nt) {
      int rn = nt * 16 + l15;
      bf16x8 bkf = *(const bf16x8*)&Ks[rn * 64 + (((c * 4 + g) ^ (rn & 7)) << 3)];
      ct[nt] = __builtin_amdgcn_mfma_f32_16x16x32_bf16(aq[c], bkf, ct[nt], 0, 0, 0);
    }

  __bf16* Pw = Ps + w * 2176;
  float rs[4] = {0.f, 0.f, 0.f, 0.f};
#pragma unroll
  for (int nt = 0; nt < 8; ++nt) {
    int kg = nt * 16 + l15;
#pragma unroll
    for (int r = 0; r < 4; ++r) {
      float p = __expf(ct[nt][r] * 0.125f - (float)kg - 2.0f);
      __bf16 pb = (__bf16)p;
      Pw[(g * 4 + r) * 136 + kg] = pb;
      rs[r] += (float)pb;
    }
  }
#pragma unroll
  for (int r = 0; r < 4; ++r) {
    float s = rs[r];
    s += __shfl_xor(s, 1, 16);
    s += __shfl_xor(s, 2, 16);
    s += __shfl_xor(s, 4, 16);
    s += __shfl_xor(s, 8, 16);
    rs[r] = 1.0f / s;
  }

  f32x4 co[4] = {};
  bf16x8 ap[4];
#pragma unroll
  for (int c = 0; c < 4; ++c) ap[c] = *(const bf16x8*)&Pw[l15 * 136 + c * 32 + g * 8];
#pragma unroll
  for (int nt = 0; nt < 4; ++nt) {
    int d = nt * 16 + l15;
#pragma unroll
    for (int c = 0; c < 4; ++c) {
      bf16x8 bv = *(const bf16x8*)&Vt[d * 128 + (((c * 4 + g) ^ (d & 7)) << 3)];
      co[nt] = __builtin_amdgcn_mfma_f32_16x16x32_bf16(ap[c], bv, co[nt], 0, 0, 0);
    }
  }

#pragma unroll
  for (int r = 0; r < 4; ++r) {
    int qg = q0 + w * 16 + g * 4 + r;
    if (qg < 1000) {
      __bf16* op = ctx + ((size_t)(b * 1000 + qg)) * 512 + h * 64 + l15;
#pragma unroll
      for (int nt = 0; nt < 4; ++nt) op[nt * 16] = (__bf16)(co[nt][r] * rs[r]);
    }
  }
}

// ---- out-projection: 64 out-cols x 128 out-rows, fp32 output ------------------
__global__ __launch_bounds__(256) void outproj_k(const __bf16* __restrict__ A,
                                                 const __bf16* __restrict__ Wo_,
                                                 const float* __restrict__ bo_,
                                                 float* __restrict__ Y) {
  __shared__ __align__(16) __bf16 Ws[64 * 512];  // 64 KB
  const int t = threadIdx.x, w = t >> 6, l = t & 63, g = l >> 4, l15 = l & 15;
  const int id = blockIdx.x;
  int low3 = id & 7, rest = id >> 3;
  int n = rest & 7, m = (rest >> 3) * 8 + low3;  // co-XCD per m
  if (m >= 63) return;                            // block-uniform exit
  const __bf16* Ab = A + (size_t)m * 128 * 512;
  int maxrow = 8000 - m * 128; if (maxrow > 128) maxrow = 128;
  const __bf16* Wt = Wo_ + (size_t)n * 64 * 512;
  float* Yp = Y + (size_t)m * 128 * 512 + n * 64;

  float bias_j[4];
#pragma unroll
  for (int j = 0; j < 4; ++j) bias_j[j] = bo_[n * 64 + j * 16 + l15];

  int r0 = w * 32 + l15, r1 = r0 + 16;
  int cr0 = (r0 < maxrow) ? r0 : (maxrow - 1);
  int cr1 = (r1 < maxrow) ? r1 : (maxrow - 1);
  const __bf16* a0p = Ab + (size_t)cr0 * 512 + g * 8;
  const __bf16* a1p = Ab + (size_t)cr1 * 512 + g * 8;
  bf16x8 a0 = *(const bf16x8*)a0p;
  bf16x8 a1 = *(const bf16x8*)a1p;

#pragma unroll
  for (int i = 0; i < 16; ++i) {
    int s = i * 256 + t;
    int row = s >> 6, u = s & 63;
    async16(Wt + (size_t)row * 512 + ((u ^ (row & 7)) << 3), &Ws[s * 8]);
  }
  __syncthreads();

  f32x4 acc[2][4] = {};
#pragma unroll
  for (int ks = 0; ks < 16; ++ks) {
    bf16x8 ca0 = a0, ca1 = a1;
    if (ks < 15) {
      a0 = *(const bf16x8*)(a0p + (ks + 1) * 32);
      a1 = *(const bf16x8*)(a1p + (ks + 1) * 32);
    }
    bf16x8 bfr[4];
#pragma unroll
    for (int j = 0; j < 4; ++j) {
      int rb = j * 16 + l15;
      int u = ks * 4 + g;
      bfr[j] = *(const bf16x8*)&Ws[rb * 512 + ((u ^ (rb & 7)) << 3)];
    }
#pragma unroll
    for (int j = 0; j < 4; ++j) {
      acc[0][j] = __builtin_amdgcn_mfma_f32_16x16x32_bf16(ca0, bfr[j], acc[0][j], 0, 0, 0);
      acc[1][j] = __builtin_amdgcn_mfma_f32_16x16x32_bf16(ca1, bfr[j], acc[1][j], 0, 0, 0);
    }
  }

#pragma unroll
  for (int strip = 0; strip < 2; ++strip)
#pragma unroll
    for (int r = 0; r < 4; ++r) {
      int lrow = w * 32 + strip * 16 + g * 4 + r;
      if (lrow < maxrow) {
#pragma unroll
        for (int j = 0; j < 4; ++j)
          Yp[(size_t)lrow * 512 + j * 16 + l15] = acc[strip][j][r] + bias_j[j];
      }
    }
}

extern "C" void kernel_launch(void* const* d_in, const int* in_sizes, int n_in,
                              void* d_out, int out_size, void* d_ws, size_t ws_size,
                              hipStream_t stream) {
  const size_t LW = (size_t)5 * 512 * 512;
  const size_t LB = (size_t)5 * 512;

  const float* x   = (const float*)d_in[0];
  const float* lg5 = (const float*)d_in[1] + LB;
  const float* lb5 = (const float*)d_in[2] + LB;
  const float* Wq5 = (const float*)d_in[3] + LW;
  const float* bq5 = (const float*)d_in[4] + LB;
  const float* Wk5 = (const float*)d_in[5] + LW;
  const float* bk5 = (const float*)d_in[6] + LB;
  const float* Wv5 = (const float*)d_in[7] + LW;
  const float* bv5 = (const float*)d_in[8] + LB;
  const float* Wo5 = (const float*)d_in[9] + LW;
  const float* bo5 = (const float*)d_in[10] + LB;
  float* out = (float*)d_out;
  __bf16* ws = (__bf16*)d_ws;

  // ws (bf16 elems): xn 4.096M | ctx 4.096M | kv 1024x1024 | Wq bf16 | (gap) | Wo bf16
  __bf16* xn  = ws;
  __bf16* ctx = ws + 4096000;
  __bf16* kvb = ws + 8192000;
  __bf16* wqb = ws + 9240576;
  __bf16* wob = wqb + 786432;

  // A: prep (weights Wq/Wo + LN all 8000 rows) || self-sufficient KV projection
  prep_kv_k<<<2640, 256, 0, stream>>>(x, lg5, lb5, Wq5, Wo5, Wk5, Wv5, bk5, bv5,
                                      wqb, wob, xn, kvb);
  // B: fused Q-projection + attention
  attn_k<<<1024, 256, 0, stream>>>(xn, wqb, bq5, kvb, ctx);
  // C: out-projection
  outproj_k<<<512, 256, 0, stream>>>(ctx, wob, bo5, out);
}

// Round 5
// 138.815 us; speedup vs baseline: 1.0482x; 1.0482x over previous
//
#include <hip/hip_runtime.h>
#include <math.h>

// StreamingTransformer: B=8, S=1000, C=512, H=8, D=64, L=6.
// Facts exploited:
//  (1) x is loop-invariant in the reference -> only layer 5 matters.
//  (2) scores = qk*0.125 + (i-j); keys j >= 128 contribute < e^-120 -> truncate
//      attention (and K/V projection) to 128 keys.
//  (3) softmax shift-invariance with analytic shift (i+2) -> no max-reduction.
// Round 9: launch-count lever is DEAD (R4: 3 launches = 145.5 vs 4 = 140). R1's
// mega_k profile (all pipes <5%, occ 23%) says phases are LATENCY-bound: serial
// stage->barrier->compute walls at 2 waves/SIMD. This round restructures attn_k:
//  - 512-thread blocks, 128 q-rows/block (Wq stage amortized 2x, grid 1024->512)
//  - K staged to a SEPARATE LDS buffer + V loaded to REGS concurrently with the
//    Wq stage (K/V stage wall vanishes under the Wq wait + q-GEMM)
//  - 80 KB LDS -> 2 blocks/CU = 4 waves/SIMD (2x latency hiding)
// prep/kv-gemm/outproj revert to the best-measured R2 form (139.6us).

typedef __bf16 bf16x8 __attribute__((ext_vector_type(8)));
typedef __bf16 bf16x4 __attribute__((ext_vector_type(4)));
typedef float f32x4 __attribute__((ext_vector_type(4)));

__device__ __forceinline__ void async16(const __bf16* g, __bf16* l) {
  __builtin_amdgcn_global_load_lds((const __attribute__((address_space(1))) void*)g,
                                   (__attribute__((address_space(3))) void*)l, 16, 0, 0);
}

// ---- prep: blocks 0..1023 = weight fp32->bf16; 1024..3023 = LN (4 rows/block) --
__global__ __launch_bounds__(256) void prep_k(const float* __restrict__ Wq, const float* __restrict__ Wk,
                                              const float* __restrict__ Wv, const float* __restrict__ Wo,
                                              __bf16* __restrict__ wdst,
                                              const float* __restrict__ x, const float* __restrict__ lg,
                                              const float* __restrict__ lb, __bf16* __restrict__ y) {
  const int bid = blockIdx.x;
  if (bid < 1024) {
    const float* src = (bid < 256) ? Wq : (bid < 512) ? Wk : (bid < 768) ? Wv : Wo;
    int idx = ((bid & 255) * 256 + threadIdx.x) * 4;
    float4 v = *(const float4*)(src + idx);
    bf16x4 o = {(__bf16)v.x, (__bf16)v.y, (__bf16)v.z, (__bf16)v.w};
    *(bf16x4*)(wdst + (size_t)(bid >> 8) * 262144 + idx) = o;
    return;
  }
  const int row = (bid - 1024) * 4 + (threadIdx.x >> 6);
  const int l = threadIdx.x & 63;
  const float* xr = x + (size_t)row * 512 + l * 8;
  float4 a = *(const float4*)xr, c = *(const float4*)(xr + 4);
  float s = a.x + a.y + a.z + a.w + c.x + c.y + c.z + c.w;
#pragma unroll
  for (int m = 1; m < 64; m <<= 1) s += __shfl_xor(s, m, 64);
  float mean = s * (1.0f / 512.0f);
  float d[8] = {a.x - mean, a.y - mean, a.z - mean, a.w - mean,
                c.x - mean, c.y - mean, c.z - mean, c.w - mean};
  float qq = 0.f;
#pragma unroll
  for (int e = 0; e < 8; ++e) qq += d[e] * d[e];
#pragma unroll
  for (int m = 1; m < 64; m <<= 1) qq += __shfl_xor(qq, m, 64);
  float rstd = rsqrtf(qq * (1.0f / 512.0f) + 1e-5f);
  float4 g0 = *(const float4*)(lg + l * 8), g1 = *(const float4*)(lg + l * 8 + 4);
  float4 b0 = *(const float4*)(lb + l * 8), b1 = *(const float4*)(lb + l * 8 + 4);
  float gg[8] = {g0.x, g0.y, g0.z, g0.w, g1.x, g1.y, g1.z, g1.w};
  float bb[8] = {b0.x, b0.y, b0.z, b0.w, b1.x, b1.y, b1.z, b1.w};
  bf16x8 o;
#pragma unroll
  for (int e = 0; e < 8; ++e) o[e] = (__bf16)(d[e] * rstd * gg[e] + bb[e]);
  *(bf16x8*)(y + (size_t)row * 512 + l * 8) = o;
}

// ---- W-resident MFMA GEMM (64 out-cols x 128 out-rows, one barrier) -----------
// PROJ=0 with idbase=512: KV projection (128 blocks). PROJ=1: out-proj, fp32 out.
template <int PROJ>
__global__ __launch_bounds__(256) void gemm_k(const __bf16* __restrict__ A,
                                              const __bf16* __restrict__ Wq_,
                                              const __bf16* __restrict__ Wkv_,
                                              const float* __restrict__ bq_,
                                              const float* __restrict__ bk_,
                                              const float* __restrict__ bv_,
                                              void* __restrict__ Yq_,
                                              __bf16* __restrict__ Ykv_,
                                              int idbase) {
  __shared__ __align__(16) __bf16 Ws[64 * 512];  // 64 KB
  const int t = threadIdx.x, w = t >> 6, l = t & 63, g = l >> 4, l15 = l & 15;
  const int id = blockIdx.x + idbase;

  const __bf16* Ab;
  const __bf16* Wt;
  const float* bp;
  int maxrow, ldY;
  void* Yp;
  if (PROJ || id < 512) {
    int low3 = id & 7, rest = id >> 3;
    int n = rest & 7, m = (rest >> 3) * 8 + low3;  // m 0..63, co-XCD per m
    if (m >= 63) return;                            // block-uniform exit
    Ab = A + (size_t)m * 128 * 512;
    maxrow = 8000 - m * 128; if (maxrow > 128) maxrow = 128;
    Wt = Wq_ + (size_t)n * 64 * 512;
    bp = bq_ + n * 64;
    ldY = 512;
    Yp = (float*)Yq_ + (size_t)m * 128 * 512 + n * 64;
  } else {
    int kid = id - 512;
    int b = kid & 7, n = kid >> 3;                  // n 0..15, co-XCD per batch
    Ab = A + (size_t)b * 1000 * 512;
    maxrow = 128;
    Wt = Wkv_ + (size_t)n * 64 * 512;
    int nc = n * 64;
    bp = (nc < 512) ? (bk_ + nc) : (bv_ + (nc - 512));
    ldY = 1024;
    Yp = Ykv_ + (size_t)b * 128 * 1024 + nc;
  }

  float bias_j[4];
#pragma unroll
  for (int j = 0; j < 4; ++j) bias_j[j] = bp[j * 16 + l15];

  int r0 = w * 32 + l15, r1 = r0 + 16;
  int cr0 = (r0 < maxrow) ? r0 : (maxrow - 1);
  int cr1 = (r1 < maxrow) ? r1 : (maxrow - 1);
  const __bf16* a0p = Ab + (size_t)cr0 * 512 + g * 8;
  const __bf16* a1p = Ab + (size_t)cr1 * 512 + g * 8;
  bf16x8 a0 = *(const bf16x8*)a0p;  // k-step 0 prefetch (before the barrier)
  bf16x8 a1 = *(const bf16x8*)a1p;

#pragma unroll
  for (int i = 0; i < 16; ++i) {
    int s = i * 256 + t;          // wave-uniform base + lane
    int row = s >> 6, u = s & 63;
    async16(Wt + (size_t)row * 512 + ((u ^ (row & 7)) << 3), &Ws[s * 8]);
  }
  __syncthreads();  // the only barrier: W resident from here on

  f32x4 acc[2][4] = {};
#pragma unroll
  for (int ks = 0; ks < 16; ++ks) {
    bf16x8 ca0 = a0, ca1 = a1;
    if (ks < 15) {                 // software-pipeline next A-frags
      a0 = *(const bf16x8*)(a0p + (ks + 1) * 32);
      a1 = *(const bf16x8*)(a1p + (ks + 1) * 32);
    }
    bf16x8 bfr[4];
#pragma unroll
    for (int j = 0; j < 4; ++j) {
      int rb = j * 16 + l15;
      int u = ks * 4 + g;
      bfr[j] = *(const bf16x8*)&Ws[rb * 512 + ((u ^ (rb & 7)) << 3)];
    }
#pragma unroll
    for (int j = 0; j < 4; ++j) {
      acc[0][j] = __builtin_amdgcn_mfma_f32_16x16x32_bf16(ca0, bfr[j], acc[0][j], 0, 0, 0);
      acc[1][j] = __builtin_amdgcn_mfma_f32_16x16x32_bf16(ca1, bfr[j], acc[1][j], 0, 0, 0);
    }
  }

#pragma unroll
  for (int strip = 0; strip < 2; ++strip)
#pragma unroll
    for (int r = 0; r < 4; ++r) {
      int lrow = w * 32 + strip * 16 + g * 4 + r;
      if (lrow < maxrow) {
#pragma unroll
        for (int j = 0; j < 4; ++j) {
          float val = acc[strip][j][r] + bias_j[j];
          if (PROJ) ((float*)Yp)[(size_t)lrow * ldY + j * 16 + l15] = val;
          else      ((__bf16*)Yp)[(size_t)lrow * ldY + j * 16 + l15] = (__bf16)val;
        }
      }
    }
}

// ---- fused Q-proj + attention: block = (b,h) x 128 q-rows, 512 threads --------
// LDS: arena 64KB (Wq, then overlay Vt 16K | Ps over dead Qs) + Ks 16KB = 80KB
// -> 2 blocks/CU = 16 waves/CU = 4 waves/SIMD. K staged + V reg-loaded
// CONCURRENTLY with the Wq stage (no separate K/V stage wall).
// id = h*64 + b*8 + qi: the 8 h-blocks sharing (b,qi)'s xn rows are co-XCD.
__global__ __launch_bounds__(512, 4) void attn_k(const __bf16* __restrict__ xn,
                                                 const __bf16* __restrict__ wq,
                                                 const float* __restrict__ bq,
                                                 const __bf16* __restrict__ kv,
                                                 __bf16* __restrict__ ctx) {
  __shared__ __align__(16) __bf16 arena[32768];  // 64 KB
  __shared__ __align__(16) __bf16 Ks[128 * 64];  // 16 KB
  const int t = threadIdx.x, w = t >> 6, l = t & 63, g = l >> 4, l15 = l & 15;
  const int id = blockIdx.x;
  const int h = id >> 6, b = (id >> 3) & 7, q0 = (id & 7) * 128;

  // -- issue ALL staging before the first barrier ------------------------------
  // Wq head-slice (64 x 512 = 64 KB) -> arena
  const __bf16* Wt = wq + (size_t)h * 64 * 512;
#pragma unroll
  for (int i = 0; i < 8; ++i) {
    int s = i * 512 + t;
    int row = s >> 6, u = s & 63;
    async16(Wt + (size_t)row * 512 + ((u ^ (row & 7)) << 3), &arena[s * 8]);
  }
  // K slice (128 x 64 = 16 KB) -> Ks (separate buffer, lives through QK)
#pragma unroll
  for (int i = 0; i < 2; ++i) {
    int s = i * 512 + t;
    int row = s >> 3, u = s & 7;
    async16(kv + (size_t)(b * 128 + row) * 1024 + h * 64 + ((u ^ (row & 7)) << 3), &Ks[s * 8]);
  }
  // V slice -> registers (scattered to LDS after the q-GEMM frees the arena)
  const int vrow = t & 127, dbase = (t >> 7) * 16;
  const __bf16* vp = kv + (size_t)(b * 128 + vrow) * 1024 + 512 + h * 64 + dbase;
  bf16x8 v0 = *(const bf16x8*)vp;
  bf16x8 v1 = *(const bf16x8*)(vp + 8);
  // A-frag prefetch: wave w owns q-rows q0 + w*16 .. +15 (clamped)
  int qr = q0 + w * 16 + l15;
  if (qr > 999) qr = 999;
  const __bf16* a0p = xn + ((size_t)(b * 1000 + qr)) * 512 + g * 8;
  bf16x8 a0 = *(const bf16x8*)a0p;
  float bias_j[4];
#pragma unroll
  for (int j = 0; j < 4; ++j) bias_j[j] = bq[h * 64 + j * 16 + l15];
  __syncthreads();  // Wq + K resident, V in regs

  // -- q-GEMM: 128 rows x 512 @ Wq_h^T -> 128 x 64 (per wave: 16 rows) ---------
  f32x4 acc[4] = {};
#pragma unroll
  for (int ks = 0; ks < 16; ++ks) {
    bf16x8 ca = a0;
    if (ks < 15) a0 = *(const bf16x8*)(a0p + (ks + 1) * 32);
    bf16x8 bfr[4];
#pragma unroll
    for (int j = 0; j < 4; ++j) {
      int rb = j * 16 + l15;
      int u = ks * 4 + g;
      bfr[j] = *(const bf16x8*)&arena[rb * 512 + ((u ^ (rb & 7)) << 3)];
    }
#pragma unroll
    for (int j = 0; j < 4; ++j)
      acc[j] = __builtin_amdgcn_mfma_f32_16x16x32_bf16(ca, bfr[j], acc[j], 0, 0, 0);
  }
  __syncthreads();  // Wq dead; arena reusable

  // -- arena overlay: Vt [0,8192) elems | Qs [8192,16384) | Ps over dead Qs ----
  __bf16* Vt = arena;            // 64 x 128
  __bf16* Qs = arena + 8192;     // 128 x 64
  __bf16* Ps = arena + 8192;     // 128 x 136 (overlays Qs AFTER aq is read)

  {  // V scatter from regs (transposed, swizzled)
#pragma unroll
    for (int e = 0; e < 8; ++e) {
      int d0 = dbase + e, d1 = dbase + 8 + e;
      Vt[d0 * 128 + (((vrow >> 3) ^ (d0 & 7)) << 3) + (vrow & 7)] = v0[e];
      Vt[d1 * 128 + (((vrow >> 3) ^ (d1 & 7)) << 3) + (vrow & 7)] = v1[e];
    }
  }
  // q-tile -> Qs (swizzled); read back own A-frags (same wave, no barrier)
#pragma unroll
  for (int j = 0; j < 4; ++j)
#pragma unroll
    for (int r = 0; r < 4; ++r) {
      int row = w * 16 + g * 4 + r, col = j * 16 + l15;
      Qs[row * 64 + (((col >> 3) ^ (row & 7)) << 3) + (col & 7)] =
          (__bf16)(acc[j][r] + bias_j[j]);
    }
  bf16x8 aq[2];
  {
    int row = w * 16 + l15;
    aq[0] = *(const bf16x8*)&Qs[row * 64 + ((g ^ (row & 7)) << 3)];
    aq[1] = *(const bf16x8*)&Qs[row * 64 + (((4 + g) ^ (row & 7)) << 3)];
  }
  __syncthreads();  // Vt visible; all aq reads done -> Qs region now dead

  // -- QK^T over 128 keys ------------------------------------------------------
  f32x4 ct[8] = {};
#pragma unroll
  for (int c = 0; c < 2; ++c)
#pragma unroll
    for (int nt = 0; nt < 8; ++nt) {
      int rn = nt * 16 + l15;
      bf16x8 bkf = *(const bf16x8*)&Ks[rn * 64 + (((c * 4 + g) ^ (rn & 7)) << 3)];
      ct[nt] = __builtin_amdgcn_mfma_f32_16x16x32_bf16(aq[c], bkf, ct[nt], 0, 0, 0);
    }

  // -- softmax (analytic shift, no max-reduction) ------------------------------
  float rs[4] = {0.f, 0.f, 0.f, 0.f};
#pragma unroll
  for (int nt = 0; nt < 8; ++nt) {
    int kg = nt * 16 + l15;
#pragma unroll
    for (int r = 0; r < 4; ++r) {
      float p = __expf(ct[nt][r] * 0.125f - (float)kg - 2.0f);
      __bf16 pb = (__bf16)p;
      Ps[(w * 16 + g * 4 + r) * 136 + kg] = pb;
      rs[r] += (float)pb;
    }
  }
#pragma unroll
  for (int r = 0; r < 4; ++r) {
    float s = rs[r];
    s += __shfl_xor(s, 1, 16);
    s += __shfl_xor(s, 2, 16);
    s += __shfl_xor(s, 4, 16);
    s += __shfl_xor(s, 8, 16);
    rs[r] = 1.0f / s;
  }

  // -- PV ----------------------------------------------------------------------
  f32x4 co[4] = {};
  bf16x8 ap[4];
#pragma unroll
  for (int c = 0; c < 4; ++c)
    ap[c] = *(const bf16x8*)&Ps[(w * 16 + l15) * 136 + c * 32 + g * 8];
#pragma unroll
  for (int nt = 0; nt < 4; ++nt) {
    int d = nt * 16 + l15;
#pragma unroll
    for (int c = 0; c < 4; ++c) {
      bf16x8 bv = *(const bf16x8*)&Vt[d * 128 + (((c * 4 + g) ^ (d & 7)) << 3)];
      co[nt] = __builtin_amdgcn_mfma_f32_16x16x32_bf16(ap[c], bv, co[nt], 0, 0, 0);
    }
  }

#pragma unroll
  for (int r = 0; r < 4; ++r) {
    int qg = q0 + w * 16 + g * 4 + r;
    if (qg < 1000) {
      __bf16* op = ctx + ((size_t)(b * 1000 + qg)) * 512 + h * 64 + l15;
#pragma unroll
      for (int nt = 0; nt < 4; ++nt) op[nt * 16] = (__bf16)(co[nt][r] * rs[r]);
    }
  }
}

extern "C" void kernel_launch(void* const* d_in, const int* in_sizes, int n_in,
                              void* d_out, int out_size, void* d_ws, size_t ws_size,
                              hipStream_t stream) {
  const float* x    = (const float*)d_in[0];
  const float* ln_g = (const float*)d_in[1];
  const float* ln_b = (const float*)d_in[2];
  const float* Wq   = (const float*)d_in[3];
  const float* bq   = (const float*)d_in[4];
  const float* Wk   = (const float*)d_in[5];
  const float* bk   = (const float*)d_in[6];
  const float* Wv   = (const float*)d_in[7];
  const float* bv   = (const float*)d_in[8];
  const float* Wo   = (const float*)d_in[9];
  const float* bo   = (const float*)d_in[10];
  float* out = (float*)d_out;
  __bf16* ws = (__bf16*)d_ws;

  // ws (bf16 elems): xn 4.096M | ctx 4.096M | kv 1024x1024 | [Wq;Wk;Wv;Wo] bf16.
  __bf16* xn  = ws;
  __bf16* ctx = ws + 4096000;   // xn stays live through attn (q-GEMM A operand)
  __bf16* kvb = ws + 8192000;
  __bf16* wqb = ws + 9240576;
  __bf16* wkv = wqb + 262144;   // [Wk;Wv] contiguous, 1024 rows
  __bf16* wob = wqb + 786432;

  const size_t LW = (size_t)5 * 512 * 512;
  const size_t LB = (size_t)5 * 512;

  prep_k<<<3024, 256, 0, stream>>>(Wq + LW, Wk + LW, Wv + LW, Wo + LW, wqb,
                                   x, ln_g + LB, ln_b + LB, xn);
  gemm_k<0><<<128, 256, 0, stream>>>(xn, nullptr, wkv, nullptr, bk + LB, bv + LB,
                                     nullptr, kvb, 512);
  attn_k<<<512, 512, 0, stream>>>(xn, wqb, bq + LB, kvb, ctx);
  gemm_k<1><<<512, 256, 0, stream>>>(ctx, wob, nullptr, bo + LB, nullptr, nullptr,
                                     out, nullptr, 0);
}